// Round 2
// baseline (1286.118 us; speedup 1.0000x reference)
//
#include <hip/hip_runtime.h>
#include <math.h>

// GCN 3-layer + maxpool + MLP head.
// ws budget ~194 MB: H (bf16) + A1 (fp32,64f) + B (fp32,128f) + O3 (bf16,256f) + CSR.

typedef unsigned short u16;
typedef unsigned int   u32;

__device__ __forceinline__ float bf2f(u16 u) {
    return __uint_as_float(((u32)u) << 16);
}
__device__ __forceinline__ u16 f2bf(float f) {
    u32 u = __float_as_uint(f);
    u32 r = (u + 0x7fffu + ((u >> 16) & 1u)) >> 16;   // round-nearest-even
    return (u16)r;
}

// ---------------- graph preprocessing ----------------

__global__ void deg_cnt_kernel(const int* __restrict__ ei, const float* __restrict__ ew,
                               float* __restrict__ deg, int* __restrict__ cnt, int E) {
    int e = blockIdx.x * blockDim.x + threadIdx.x;
    if (e < E) {
        int d = ei[E + e];                 // dst row of edge_index [2,E]
        atomicAdd(&deg[d], ew[e]);
        atomicAdd(&cnt[d], 1);
    }
}

__global__ void finish_deg_kernel(const float* __restrict__ deg, float* __restrict__ dinv, int n) {
    int i = blockIdx.x * blockDim.x + threadIdx.x;
    if (i < n) dinv[i] = rsqrtf(deg[i] + 1.0f);
}

// exclusive scan of cnt[] -> off[], 1024 elems per block
__global__ void scan_partial_kernel(const int* __restrict__ cnt, int* __restrict__ off,
                                    int* __restrict__ bsums, int n) {
    __shared__ int ts[256];
    int t = threadIdx.x;
    int base = blockIdx.x * 1024;
    int v[4]; int s = 0;
    for (int j = 0; j < 4; ++j) {
        int i = base + t * 4 + j;
        v[j] = (i < n) ? cnt[i] : 0;
        s += v[j];
    }
    ts[t] = s;
    __syncthreads();
    for (int st = 1; st < 256; st <<= 1) {
        int x = (t >= st) ? ts[t - st] : 0;
        __syncthreads();
        ts[t] += x;
        __syncthreads();
    }
    int excl = ts[t] - s;
    if (t == 255) bsums[blockIdx.x] = ts[255];
    int run = excl;
    for (int j = 0; j < 4; ++j) {
        int i = base + t * 4 + j;
        if (i < n) off[i] = run;
        run += v[j];
    }
}

__global__ void scan_sums_kernel(int* __restrict__ bsums, int nb) {
    __shared__ int ts[128];
    int t = threadIdx.x;
    int v = (t < nb) ? bsums[t] : 0;
    ts[t] = v;
    __syncthreads();
    for (int st = 1; st < 128; st <<= 1) {
        int x = (t >= st) ? ts[t - st] : 0;
        __syncthreads();
        ts[t] += x;
        __syncthreads();
    }
    if (t < nb) bsums[t] = ts[t] - v;   // exclusive
}

__global__ void scan_add_kernel(int* __restrict__ off, const int* __restrict__ bsums, int n) {
    int i = blockIdx.x * blockDim.x + threadIdx.x;
    if (i < n) off[i] += bsums[i >> 10];
}

__global__ void build_csr_kernel(const int* __restrict__ ei, const float* __restrict__ ew,
                                 const float* __restrict__ dinv, const int* __restrict__ off,
                                 int* __restrict__ cur, int* __restrict__ ssrc,
                                 float* __restrict__ snrm, int E) {
    int e = blockIdx.x * blockDim.x + threadIdx.x;
    if (e < E) {
        int s = ei[e], d = ei[E + e];
        float nrm = dinv[s] * ew[e] * dinv[d];
        int pos = off[d] + atomicAdd(&cur[d], 1);
        ssrc[pos] = s;
        snrm[pos] = nrm;
    }
}

// ---------------- per-layer compute ----------------

// h = act @ W (bf16 H out); OUT = h*dinv^2 + b  (self-loop + bias init)
template<int FIN, int FOUT, bool RELU_IN, bool OUT_BF>
__global__ void gemm_selfinit_kernel(const float* __restrict__ in, const float* __restrict__ W,
                                     const float* __restrict__ b, const float* __restrict__ dinv,
                                     u16* __restrict__ Hb, void* __restrict__ OUT, int n) {
    constexpr int TPN = FOUT / 4;       // threads per node (4 outputs each)
    constexpr int NPB = 256 / TPN;      // nodes per block
    __shared__ float xs[NPB][FIN + 1];
    int t = threadIdx.x;
    int gbase = blockIdx.x * NPB;
    for (int l = t; l < NPB * FIN; l += 256) {
        int r = l / FIN, k = l - r * FIN;
        int gn = gbase + r;
        float v = (gn < n) ? in[(size_t)gn * FIN + k] : 0.0f;
        if (RELU_IN) v = fmaxf(v, 0.0f);
        xs[r][k] = v;
    }
    __syncthreads();
    int r = t / TPN;
    int j4 = (t % TPN) * 4;
    float4 acc = make_float4(0.f, 0.f, 0.f, 0.f);
    #pragma unroll 4
    for (int k = 0; k < FIN; ++k) {
        float xk = xs[r][k];
        float4 w = *reinterpret_cast<const float4*>(&W[k * FOUT + j4]);
        acc.x += xk * w.x; acc.y += xk * w.y; acc.z += xk * w.z; acc.w += xk * w.w;
    }
    int gnode = gbase + r;
    if (gnode < n) {
        ushort4 hb;
        hb.x = f2bf(acc.x); hb.y = f2bf(acc.y); hb.z = f2bf(acc.z); hb.w = f2bf(acc.w);
        *reinterpret_cast<ushort4*>(&Hb[(size_t)gnode * FOUT + j4]) = hb;
        float di = dinv[gnode];
        float d2 = di * di;
        float4 bb = *reinterpret_cast<const float4*>(&b[j4]);
        float ox = acc.x * d2 + bb.x;
        float oy = acc.y * d2 + bb.y;
        float oz = acc.z * d2 + bb.z;
        float ow = acc.w * d2 + bb.w;
        if (OUT_BF) {
            ushort4 ob;
            ob.x = f2bf(ox); ob.y = f2bf(oy); ob.z = f2bf(oz); ob.w = f2bf(ow);
            *reinterpret_cast<ushort4*>(&((u16*)OUT)[(size_t)gnode * FOUT + j4]) = ob;
        } else {
            float4 o = make_float4(ox, oy, oz, ow);
            *reinterpret_cast<float4*>(&((float*)OUT)[(size_t)gnode * FOUT + j4]) = o;
        }
    }
}

// OUT[i] += sum over incoming edges of H[src]*norm (CSR-by-dst, no atomics)
template<int FOUT, bool OUT_BF>
__global__ void agg_kernel(const u16* __restrict__ Hb, const int* __restrict__ off,
                           const int* __restrict__ cnt, const int* __restrict__ ssrc,
                           const float* __restrict__ snrm, void* __restrict__ OUT, int n) {
    constexpr int TPN = FOUT / 4;
    constexpr int NPB = 256 / TPN;
    int t = threadIdx.x;
    int node = blockIdx.x * NPB + t / TPN;
    if (node >= n) return;
    int j4 = (t % TPN) * 4;
    int start = off[node], num = cnt[node];
    float4 acc = make_float4(0.f, 0.f, 0.f, 0.f);
    for (int e = start; e < start + num; ++e) {
        int s = ssrc[e];
        float w = snrm[e];
        ushort4 hv = *reinterpret_cast<const ushort4*>(&Hb[(size_t)s * FOUT + j4]);
        acc.x += w * bf2f(hv.x);
        acc.y += w * bf2f(hv.y);
        acc.z += w * bf2f(hv.z);
        acc.w += w * bf2f(hv.w);
    }
    if (OUT_BF) {
        u16* op = &((u16*)OUT)[(size_t)node * FOUT + j4];
        ushort4 o = *reinterpret_cast<const ushort4*>(op);
        ushort4 no;
        no.x = f2bf(bf2f(o.x) + acc.x);
        no.y = f2bf(bf2f(o.y) + acc.y);
        no.z = f2bf(bf2f(o.z) + acc.z);
        no.w = f2bf(bf2f(o.w) + acc.w);
        *reinterpret_cast<ushort4*>(op) = no;
    } else {
        float4* op = reinterpret_cast<float4*>(&((float*)OUT)[(size_t)node * FOUT + j4]);
        float4 o = *op;
        o.x += acc.x; o.y += acc.y; o.z += acc.z; o.w += acc.w;
        *op = o;
    }
}

// ---------------- pooling + head ----------------

__global__ void maxpool_kernel(const u16* __restrict__ Ob, float* __restrict__ g, int n) {
    int f = threadIdx.x;                // 256 features
    float m = 0.0f;                     // relu folded in (max >= 0)
    for (int i = blockIdx.x; i < n; i += gridDim.x)
        m = fmaxf(m, bf2f(Ob[(size_t)i * 256 + f]));
    atomicMax((int*)&g[f], __float_as_int(m));   // valid: values >= 0
}

__global__ void head_kernel(const float* __restrict__ g, const float* __restrict__ Wl1,
                            const float* __restrict__ bl1, const float* __restrict__ Wl2,
                            const float* __restrict__ bl2, float* __restrict__ out) {
    __shared__ float gs[256];
    __shared__ float ys[128];
    __shared__ float ls[10];
    int t = threadIdx.x;
    gs[t] = g[t];
    __syncthreads();
    if (t < 128) {
        float acc = bl1[t];
        for (int k = 0; k < 256; ++k) acc += gs[k] * Wl1[k * 128 + t];
        ys[t] = fmaxf(acc, 0.0f);
    }
    __syncthreads();
    if (t < 10) {
        float acc = bl2[t];
        for (int j = 0; j < 128; ++j) acc += ys[j] * Wl2[j * 10 + t];
        ls[t] = acc;
    }
    __syncthreads();
    if (t == 0) {
        float m = ls[0];
        for (int c = 1; c < 10; ++c) m = fmaxf(m, ls[c]);
        float se = 0.0f;
        for (int c = 0; c < 10; ++c) se += expf(ls[c] - m);
        float lse = logf(se);
        for (int c = 0; c < 10; ++c) out[c] = ls[c] - m - lse;
    }
}

// ---------------- launch ----------------

static inline int cdiv(int a, int b) { return (a + b - 1) / b; }

extern "C" void kernel_launch(void* const* d_in, const int* in_sizes, int n_in,
                              void* d_out, int out_size, void* d_ws, size_t ws_size,
                              hipStream_t stream) {
    const float* x   = (const float*)d_in[0];
    const int*   ei  = (const int*)d_in[1];
    const float* ew  = (const float*)d_in[2];
    const float* W1  = (const float*)d_in[3];
    const float* b1  = (const float*)d_in[4];
    const float* W2  = (const float*)d_in[5];
    const float* b2  = (const float*)d_in[6];
    const float* W3  = (const float*)d_in[7];
    const float* b3  = (const float*)d_in[8];
    const float* Wl1 = (const float*)d_in[9];
    const float* bl1 = (const float*)d_in[10];
    const float* Wl2 = (const float*)d_in[11];
    const float* bl2 = (const float*)d_in[12];

    const int n = in_sizes[0] / 128;   // 100000
    const int E = in_sizes[1] / 2;     // 1600000

    char* p = (char*)d_ws;
    auto alloc = [&](size_t bytes) { char* q = p; p += (bytes + 255) & ~(size_t)255; return q; };
    float* deg   = (float*)alloc((size_t)n * 4);
    float* dinv  = (float*)alloc((size_t)n * 4);
    int*   cnt   = (int*)  alloc((size_t)n * 4);
    int*   off   = (int*)  alloc((size_t)n * 4);
    int*   cur   = (int*)  alloc((size_t)n * 4);
    int*   bsums = (int*)  alloc(256 * 4);
    int*   ssrc  = (int*)  alloc((size_t)E * 4);
    float* snrm  = (float*)alloc((size_t)E * 4);
    u16*   Hb    = (u16*)  alloc((size_t)n * 256 * 2);   // 51.2 MB
    float* A1    = (float*)alloc((size_t)n * 64 * 4);    // 25.6 MB
    float* B     = (float*)alloc((size_t)n * 128 * 4);   // 51.2 MB
    u16*   O3b   = (u16*)  alloc((size_t)n * 256 * 2);   // 51.2 MB
    float* g     = (float*)alloc(256 * 4);
    // total ~194.4 MB

    hipMemsetAsync(deg, 0, (size_t)n * 4, stream);
    hipMemsetAsync(cnt, 0, (size_t)n * 4, stream);
    hipMemsetAsync(cur, 0, (size_t)n * 4, stream);
    hipMemsetAsync(g,   0, 256 * 4, stream);

    int eb = cdiv(E, 256);
    deg_cnt_kernel<<<eb, 256, 0, stream>>>(ei, ew, deg, cnt, E);
    finish_deg_kernel<<<cdiv(n, 256), 256, 0, stream>>>(deg, dinv, n);

    int nchunks = cdiv(n, 1024);   // 98
    scan_partial_kernel<<<nchunks, 256, 0, stream>>>(cnt, off, bsums, n);
    scan_sums_kernel<<<1, 128, 0, stream>>>(bsums, nchunks);
    scan_add_kernel<<<cdiv(n, 256), 256, 0, stream>>>(off, bsums, n);
    build_csr_kernel<<<eb, 256, 0, stream>>>(ei, ew, dinv, off, cur, ssrc, snrm, E);

    // layer 1: 128 -> 64  (in fp32 x, out fp32 A1)
    gemm_selfinit_kernel<128, 64, false, false><<<cdiv(n, 16), 256, 0, stream>>>(x, W1, b1, dinv, Hb, A1, n);
    agg_kernel<64, false><<<cdiv(n, 16), 256, 0, stream>>>(Hb, off, cnt, ssrc, snrm, A1, n);
    // layer 2: 64 -> 128  (in A1 +relu, out fp32 B)
    gemm_selfinit_kernel<64, 128, true, false><<<cdiv(n, 8), 256, 0, stream>>>(A1, W2, b2, dinv, Hb, B, n);
    agg_kernel<128, false><<<cdiv(n, 8), 256, 0, stream>>>(Hb, off, cnt, ssrc, snrm, B, n);
    // layer 3: 128 -> 256 (in B +relu, out bf16 O3b)
    gemm_selfinit_kernel<128, 256, true, true><<<cdiv(n, 4), 256, 0, stream>>>(B, W3, b3, dinv, Hb, O3b, n);
    agg_kernel<256, true><<<cdiv(n, 4), 256, 0, stream>>>(Hb, off, cnt, ssrc, snrm, O3b, n);

    maxpool_kernel<<<256, 256, 0, stream>>>(O3b, g, n);
    head_kernel<<<1, 256, 0, stream>>>(g, Wl1, bl1, Wl2, bl2, (float*)d_out);
}

// Round 3
// 839.510 us; speedup vs baseline: 1.5320x; 1.5320x over previous
//
#include <hip/hip_runtime.h>
#include <math.h>

// GCN 3-layer + maxpool + MLP head.
// GEMMs via bf16 MFMA 16x16x32 (A and W pre-swizzled with the SAME k-permutation,
// so any k-bijection cancels; C/D layout is the HW-verified one).
// ws ~195 MB: CSR + Hb(bf16) + A1(fp32) + B(fp32) + O3(bf16) + W-fragment repacks.

typedef unsigned short u16;
typedef unsigned int   u32;

typedef short bf16x8 __attribute__((ext_vector_type(8)));
typedef float f32x4  __attribute__((ext_vector_type(4)));

__device__ __forceinline__ float bf2f(u16 u) {
    return __uint_as_float(((u32)u) << 16);
}
__device__ __forceinline__ u16 f2bf(float f) {
    u32 u = __float_as_uint(f);
    u32 r = (u + 0x7fffu + ((u >> 16) & 1u)) >> 16;   // round-nearest-even
    return (u16)r;
}

// ---------------- graph preprocessing ----------------

__global__ void deg_cnt_kernel(const int* __restrict__ ei, const float* __restrict__ ew,
                               float* __restrict__ deg, int* __restrict__ cnt, int E) {
    int e = blockIdx.x * blockDim.x + threadIdx.x;
    if (e < E) {
        int d = ei[E + e];                 // dst row of edge_index [2,E]
        atomicAdd(&deg[d], ew[e]);
        atomicAdd(&cnt[d], 1);
    }
}

__global__ void finish_deg_kernel(const float* __restrict__ deg, float* __restrict__ dinv, int n) {
    int i = blockIdx.x * blockDim.x + threadIdx.x;
    if (i < n) dinv[i] = rsqrtf(deg[i] + 1.0f);
}

// exclusive scan of cnt[] -> off[], 1024 elems per block
__global__ void scan_partial_kernel(const int* __restrict__ cnt, int* __restrict__ off,
                                    int* __restrict__ bsums, int n) {
    __shared__ int ts[256];
    int t = threadIdx.x;
    int base = blockIdx.x * 1024;
    int v[4]; int s = 0;
    for (int j = 0; j < 4; ++j) {
        int i = base + t * 4 + j;
        v[j] = (i < n) ? cnt[i] : 0;
        s += v[j];
    }
    ts[t] = s;
    __syncthreads();
    for (int st = 1; st < 256; st <<= 1) {
        int x = (t >= st) ? ts[t - st] : 0;
        __syncthreads();
        ts[t] += x;
        __syncthreads();
    }
    int excl = ts[t] - s;
    if (t == 255) bsums[blockIdx.x] = ts[255];
    int run = excl;
    for (int j = 0; j < 4; ++j) {
        int i = base + t * 4 + j;
        if (i < n) off[i] = run;
        run += v[j];
    }
}

__global__ void scan_sums_kernel(int* __restrict__ bsums, int nb) {
    __shared__ int ts[128];
    int t = threadIdx.x;
    int v = (t < nb) ? bsums[t] : 0;
    ts[t] = v;
    __syncthreads();
    for (int st = 1; st < 128; st <<= 1) {
        int x = (t >= st) ? ts[t - st] : 0;
        __syncthreads();
        ts[t] += x;
        __syncthreads();
    }
    if (t < nb) bsums[t] = ts[t] - v;   // exclusive
}

__global__ void scan_add_kernel(int* __restrict__ off, const int* __restrict__ bsums, int n) {
    int i = blockIdx.x * blockDim.x + threadIdx.x;
    if (i < n) off[i] += bsums[i >> 10];
}

__global__ void build_csr_kernel(const int* __restrict__ ei, const float* __restrict__ ew,
                                 const float* __restrict__ dinv, const int* __restrict__ off,
                                 int* __restrict__ cur, int* __restrict__ ssrc,
                                 float* __restrict__ snrm, int E) {
    int e = blockIdx.x * blockDim.x + threadIdx.x;
    if (e < E) {
        int s = ei[e], d = ei[E + e];
        float nrm = dinv[s] * ew[e] * dinv[d];
        int pos = off[d] + atomicAdd(&cur[d], 1);
        ssrc[pos] = s;
        snrm[pos] = nrm;
    }
}

// ---------------- W fragment repack (fp32 [K][N] -> bf16 MFMA B-fragments) ----------------
// Wf[t][s][lane][j] = bf16( W[s*32 + 8*(lane>>4) + j][t*16 + (lane&15)] )
template<int FIN, int FOUT>
__global__ void wconv_kernel(const float* __restrict__ W, u16* __restrict__ Wf) {
    int t = blockIdx.x;          // n-tile (FOUT/16)
    int s = blockIdx.y;          // k-step (FIN/32)
    int l = threadIdx.x;         // lane 0..63
    int col = t * 16 + (l & 15);
    int k0 = s * 32 + 8 * (l >> 4);
    u32 packed[4];
    for (int jj = 0; jj < 4; ++jj) {
        u16 lo = f2bf(W[(size_t)(k0 + 2 * jj) * FOUT + col]);
        u16 hi = f2bf(W[(size_t)(k0 + 2 * jj + 1) * FOUT + col]);
        packed[jj] = (u32)lo | ((u32)hi << 16);
    }
    u32* dst = (u32*)&Wf[(((size_t)t * (FIN / 32) + s) * 64 + l) * 8];
    dst[0] = packed[0]; dst[1] = packed[1]; dst[2] = packed[2]; dst[3] = packed[3];
}

// ---------------- MFMA GEMM + self-loop epilogue ----------------
// h = relu?(in) @ W ; Hb = bf16(h) ; OUT = h*dinv^2 + b
template<int FIN, int FOUT, bool RELU_IN, bool OUT_BF>
__global__ __launch_bounds__(256)
void gemm_mfma_kernel(const float* __restrict__ in, const u16* __restrict__ Wf,
                      const float* __restrict__ b, const float* __restrict__ dinv,
                      u16* __restrict__ Hb, void* __restrict__ OUT, int n) {
    constexpr int KS = FIN / 32;   // k-steps
    constexpr int NT = FOUT / 16;  // n-tiles
    __shared__ u16 Asw[4][KS][64][8];   // per-wave A fragments, 64*FIN*2 bytes
    int tid = threadIdx.x;
    int gbase = blockIdx.x * 64;

    // stage A: coalesced float4 row loads -> bf16 fragment-order LDS (b64 writes)
    constexpr int Q = FIN / 4;     // float4 per row
    for (int idx = tid; idx < 64 * Q; idx += 256) {
        int m = idx / Q, q = idx - m * Q;
        int gn = gbase + m;
        float4 v = make_float4(0.f, 0.f, 0.f, 0.f);
        if (gn < n) v = *reinterpret_cast<const float4*>(&in[(size_t)gn * FIN + 4 * q]);
        if (RELU_IN) {
            v.x = fmaxf(v.x, 0.f); v.y = fmaxf(v.y, 0.f);
            v.z = fmaxf(v.z, 0.f); v.w = fmaxf(v.w, 0.f);
        }
        int w = m >> 4, lr = m & 15;
        int s = q >> 3;
        int lane_hi = (q & 7) >> 1;
        int j0 = 4 * (q & 1);
        int l = (lane_hi << 4) | lr;
        u32 p0 = (u32)f2bf(v.x) | ((u32)f2bf(v.y) << 16);
        u32 p1 = (u32)f2bf(v.z) | ((u32)f2bf(v.w) << 16);
        uint2* dst = reinterpret_cast<uint2*>(&Asw[w][s][l][j0]);
        *dst = make_uint2(p0, p1);
    }
    __syncthreads();

    int w = tid >> 6, lane = tid & 63;
    int nodeq = gbase + w * 16 + ((lane >> 4) << 2);   // node for r=0

    bf16x8 a[KS];
    #pragma unroll
    for (int s = 0; s < KS; ++s)
        a[s] = *reinterpret_cast<const bf16x8*>(&Asw[w][s][lane][0]);

    float d2[4];
    #pragma unroll
    for (int r = 0; r < 4; ++r) {
        int node = nodeq + r;
        float di = (node < n) ? dinv[node] : 0.f;
        d2[r] = di * di;
    }

    int col0 = lane & 15;
    #pragma unroll
    for (int t = 0; t < NT; ++t) {
        f32x4 acc = {0.f, 0.f, 0.f, 0.f};
        #pragma unroll
        for (int s = 0; s < KS; ++s) {
            bf16x8 bf = *reinterpret_cast<const bf16x8*>(&Wf[(((size_t)t * KS + s) * 64 + lane) * 8]);
            acc = __builtin_amdgcn_mfma_f32_16x16x32_bf16(a[s], bf, acc, 0, 0, 0);
        }
        int col = t * 16 + col0;
        float bb = b[col];
        #pragma unroll
        for (int r = 0; r < 4; ++r) {
            int node = nodeq + r;
            if (node < n) {
                float h = acc[r];
                Hb[(size_t)node * FOUT + col] = f2bf(h);
                float o = h * d2[r] + bb;
                if (OUT_BF) ((u16*)OUT)[(size_t)node * FOUT + col] = f2bf(o);
                else        ((float*)OUT)[(size_t)node * FOUT + col] = o;
            }
        }
    }
}

// OUT[i] += sum over incoming edges of H[src]*norm (CSR-by-dst, no atomics)
template<int FOUT, bool OUT_BF>
__global__ void agg_kernel(const u16* __restrict__ Hb, const int* __restrict__ off,
                           const int* __restrict__ cnt, const int* __restrict__ ssrc,
                           const float* __restrict__ snrm, void* __restrict__ OUT, int n) {
    constexpr int TPN = FOUT / 4;
    constexpr int NPB = 256 / TPN;
    int t = threadIdx.x;
    int node = blockIdx.x * NPB + t / TPN;
    if (node >= n) return;
    int j4 = (t % TPN) * 4;
    int start = off[node], num = cnt[node];
    float4 acc = make_float4(0.f, 0.f, 0.f, 0.f);
    for (int e = start; e < start + num; ++e) {
        int s = ssrc[e];
        float w = snrm[e];
        ushort4 hv = *reinterpret_cast<const ushort4*>(&Hb[(size_t)s * FOUT + j4]);
        acc.x += w * bf2f(hv.x);
        acc.y += w * bf2f(hv.y);
        acc.z += w * bf2f(hv.z);
        acc.w += w * bf2f(hv.w);
    }
    if (OUT_BF) {
        u16* op = &((u16*)OUT)[(size_t)node * FOUT + j4];
        ushort4 o = *reinterpret_cast<const ushort4*>(op);
        ushort4 no;
        no.x = f2bf(bf2f(o.x) + acc.x);
        no.y = f2bf(bf2f(o.y) + acc.y);
        no.z = f2bf(bf2f(o.z) + acc.z);
        no.w = f2bf(bf2f(o.w) + acc.w);
        *reinterpret_cast<ushort4*>(op) = no;
    } else {
        float4* op = reinterpret_cast<float4*>(&((float*)OUT)[(size_t)node * FOUT + j4]);
        float4 o = *op;
        o.x += acc.x; o.y += acc.y; o.z += acc.z; o.w += acc.w;
        *op = o;
    }
}

// ---------------- pooling + head ----------------

__global__ void maxpool_kernel(const u16* __restrict__ Ob, float* __restrict__ g, int n) {
    int f = threadIdx.x;                // 256 features
    float m = 0.0f;                     // relu folded in (max >= 0)
    for (int i = blockIdx.x; i < n; i += gridDim.x)
        m = fmaxf(m, bf2f(Ob[(size_t)i * 256 + f]));
    atomicMax((int*)&g[f], __float_as_int(m));   // valid: values >= 0
}

__global__ void head_kernel(const float* __restrict__ g, const float* __restrict__ Wl1,
                            const float* __restrict__ bl1, const float* __restrict__ Wl2,
                            const float* __restrict__ bl2, float* __restrict__ out) {
    __shared__ float gs[256];
    __shared__ float ys[128];
    __shared__ float ls[10];
    int t = threadIdx.x;
    gs[t] = g[t];
    __syncthreads();
    if (t < 128) {
        float acc = bl1[t];
        for (int k = 0; k < 256; ++k) acc += gs[k] * Wl1[k * 128 + t];
        ys[t] = fmaxf(acc, 0.0f);
    }
    __syncthreads();
    if (t < 10) {
        float acc = bl2[t];
        for (int j = 0; j < 128; ++j) acc += ys[j] * Wl2[j * 10 + t];
        ls[t] = acc;
    }
    __syncthreads();
    if (t == 0) {
        float m = ls[0];
        for (int c = 1; c < 10; ++c) m = fmaxf(m, ls[c]);
        float se = 0.0f;
        for (int c = 0; c < 10; ++c) se += expf(ls[c] - m);
        float lse = logf(se);
        for (int c = 0; c < 10; ++c) out[c] = ls[c] - m - lse;
    }
}

// ---------------- launch ----------------

static inline int cdiv(int a, int b) { return (a + b - 1) / b; }

extern "C" void kernel_launch(void* const* d_in, const int* in_sizes, int n_in,
                              void* d_out, int out_size, void* d_ws, size_t ws_size,
                              hipStream_t stream) {
    const float* x   = (const float*)d_in[0];
    const int*   ei  = (const int*)d_in[1];
    const float* ew  = (const float*)d_in[2];
    const float* W1  = (const float*)d_in[3];
    const float* b1  = (const float*)d_in[4];
    const float* W2  = (const float*)d_in[5];
    const float* b2  = (const float*)d_in[6];
    const float* W3  = (const float*)d_in[7];
    const float* b3  = (const float*)d_in[8];
    const float* Wl1 = (const float*)d_in[9];
    const float* bl1 = (const float*)d_in[10];
    const float* Wl2 = (const float*)d_in[11];
    const float* bl2 = (const float*)d_in[12];

    const int n = in_sizes[0] / 128;   // 100000
    const int E = in_sizes[1] / 2;     // 1600000

    char* p = (char*)d_ws;
    auto alloc = [&](size_t bytes) { char* q = p; p += (bytes + 255) & ~(size_t)255; return q; };
    float* deg   = (float*)alloc((size_t)n * 4);
    float* dinv  = (float*)alloc((size_t)n * 4);
    int*   cnt   = (int*)  alloc((size_t)n * 4);
    int*   off   = (int*)  alloc((size_t)n * 4);
    int*   cur   = (int*)  alloc((size_t)n * 4);
    int*   bsums = (int*)  alloc(256 * 4);
    int*   ssrc  = (int*)  alloc((size_t)E * 4);
    float* snrm  = (float*)alloc((size_t)E * 4);
    u16*   Hb    = (u16*)  alloc((size_t)n * 256 * 2);   // 51.2 MB
    float* A1    = (float*)alloc((size_t)n * 64 * 4);    // 25.6 MB
    float* B     = (float*)alloc((size_t)n * 128 * 4);   // 51.2 MB
    u16*   O3b   = (u16*)  alloc((size_t)n * 256 * 2);   // 51.2 MB
    u16*   W1f   = (u16*)  alloc((size_t)128 * 64 * 2);
    u16*   W2f   = (u16*)  alloc((size_t)64 * 128 * 2);
    u16*   W3f   = (u16*)  alloc((size_t)128 * 256 * 2);
    float* g     = (float*)alloc(256 * 4);
    // total ~195 MB

    hipMemsetAsync(deg, 0, (size_t)n * 4, stream);
    hipMemsetAsync(cnt, 0, (size_t)n * 4, stream);
    hipMemsetAsync(cur, 0, (size_t)n * 4, stream);
    hipMemsetAsync(g,   0, 256 * 4, stream);

    int eb = cdiv(E, 256);
    deg_cnt_kernel<<<eb, 256, 0, stream>>>(ei, ew, deg, cnt, E);
    finish_deg_kernel<<<cdiv(n, 256), 256, 0, stream>>>(deg, dinv, n);

    int nchunks = cdiv(n, 1024);   // 98
    scan_partial_kernel<<<nchunks, 256, 0, stream>>>(cnt, off, bsums, n);
    scan_sums_kernel<<<1, 128, 0, stream>>>(bsums, nchunks);
    scan_add_kernel<<<cdiv(n, 256), 256, 0, stream>>>(off, bsums, n);
    build_csr_kernel<<<eb, 256, 0, stream>>>(ei, ew, dinv, off, cur, ssrc, snrm, E);

    // W fragment repacks (tiny)
    wconv_kernel<128, 64><<<dim3(64 / 16, 128 / 32), 64, 0, stream>>>(W1, W1f);
    wconv_kernel<64, 128><<<dim3(128 / 16, 64 / 32), 64, 0, stream>>>(W2, W2f);
    wconv_kernel<128, 256><<<dim3(256 / 16, 128 / 32), 64, 0, stream>>>(W3, W3f);

    // layer 1: 128 -> 64  (in fp32 x, out fp32 A1)
    gemm_mfma_kernel<128, 64, false, false><<<cdiv(n, 64), 256, 0, stream>>>(x, W1f, b1, dinv, Hb, A1, n);
    agg_kernel<64, false><<<cdiv(n, 16), 256, 0, stream>>>(Hb, off, cnt, ssrc, snrm, A1, n);
    // layer 2: 64 -> 128  (in A1 +relu, out fp32 B)
    gemm_mfma_kernel<64, 128, true, false><<<cdiv(n, 64), 256, 0, stream>>>(A1, W2f, b2, dinv, Hb, B, n);
    agg_kernel<128, false><<<cdiv(n, 8), 256, 0, stream>>>(Hb, off, cnt, ssrc, snrm, B, n);
    // layer 3: 128 -> 256 (in B +relu, out bf16 O3b)
    gemm_mfma_kernel<128, 256, true, true><<<cdiv(n, 64), 256, 0, stream>>>(B, W3f, b3, dinv, Hb, O3b, n);
    agg_kernel<256, true><<<cdiv(n, 4), 256, 0, stream>>>(Hb, off, cnt, ssrc, snrm, O3b, n);

    maxpool_kernel<<<256, 256, 0, stream>>>(O3b, g, n);
    head_kernel<<<1, 256, 0, stream>>>(g, Wl1, bl1, Wl2, bl2, (float*)d_out);
}

// Round 4
// 602.990 us; speedup vs baseline: 2.1329x; 1.3922x over previous
//
#include <hip/hip_runtime.h>
#include <math.h>

// GCN 3-layer + maxpool + MLP head.
// Aggregate-BEFORE-GEMM restructure (GCN linearity): per layer
//   z = segsum(r[src]*norm) + r*dinv^2   (agg on INPUT feature dim)
//   r_next = relu(z @ W + b)             (bf16 MFMA GEMM, relu fused)
// Layer-3 GEMM fuses global max-pool (no O3 materialization).
// All inter-kernel tensors bf16. ws ~143 MB.

typedef unsigned short u16;
typedef unsigned int   u32;

typedef short bf16x8 __attribute__((ext_vector_type(8)));
typedef float f32x4  __attribute__((ext_vector_type(4)));

__device__ __forceinline__ float bf2f(u16 u) {
    return __uint_as_float(((u32)u) << 16);
}
__device__ __forceinline__ u16 f2bf(float f) {
    u32 u = __float_as_uint(f);
    u32 r = (u + 0x7fffu + ((u >> 16) & 1u)) >> 16;   // round-nearest-even
    return (u16)r;
}

// ---------------- graph preprocessing ----------------

__global__ void deg_cnt_kernel(const int* __restrict__ ei, const float* __restrict__ ew,
                               float* __restrict__ deg, int* __restrict__ cnt, int E) {
    int e = blockIdx.x * blockDim.x + threadIdx.x;
    if (e < E) {
        int d = ei[E + e];                 // dst row of edge_index [2,E]
        atomicAdd(&deg[d], ew[e]);
        atomicAdd(&cnt[d], 1);
    }
}

__global__ void finish_deg_kernel(const float* __restrict__ deg, float* __restrict__ dinv, int n) {
    int i = blockIdx.x * blockDim.x + threadIdx.x;
    if (i < n) dinv[i] = rsqrtf(deg[i] + 1.0f);
}

// exclusive scan of cnt[] -> off[], 1024 elems per block
__global__ void scan_partial_kernel(const int* __restrict__ cnt, int* __restrict__ off,
                                    int* __restrict__ bsums, int n) {
    __shared__ int ts[256];
    int t = threadIdx.x;
    int base = blockIdx.x * 1024;
    int v[4]; int s = 0;
    for (int j = 0; j < 4; ++j) {
        int i = base + t * 4 + j;
        v[j] = (i < n) ? cnt[i] : 0;
        s += v[j];
    }
    ts[t] = s;
    __syncthreads();
    for (int st = 1; st < 256; st <<= 1) {
        int x = (t >= st) ? ts[t - st] : 0;
        __syncthreads();
        ts[t] += x;
        __syncthreads();
    }
    int excl = ts[t] - s;
    if (t == 255) bsums[blockIdx.x] = ts[255];
    int run = excl;
    for (int j = 0; j < 4; ++j) {
        int i = base + t * 4 + j;
        if (i < n) off[i] = run;
        run += v[j];
    }
}

__global__ void scan_sums_kernel(int* __restrict__ bsums, int nb) {
    __shared__ int ts[128];
    int t = threadIdx.x;
    int v = (t < nb) ? bsums[t] : 0;
    ts[t] = v;
    __syncthreads();
    for (int st = 1; st < 128; st <<= 1) {
        int x = (t >= st) ? ts[t - st] : 0;
        __syncthreads();
        ts[t] += x;
        __syncthreads();
    }
    if (t < nb) bsums[t] = ts[t] - v;   // exclusive
}

__global__ void scan_add_kernel(int* __restrict__ off, const int* __restrict__ bsums, int n) {
    int i = blockIdx.x * blockDim.x + threadIdx.x;
    if (i < n) off[i] += bsums[i >> 10];
}

// combined payload: edge2[pos] = {src, bits(norm)}
__global__ void build_csr_kernel(const int* __restrict__ ei, const float* __restrict__ ew,
                                 const float* __restrict__ dinv, const int* __restrict__ off,
                                 int* __restrict__ cur, uint2* __restrict__ edge2, int E) {
    int e = blockIdx.x * blockDim.x + threadIdx.x;
    if (e < E) {
        int s = ei[e], d = ei[E + e];
        float nrm = dinv[s] * ew[e] * dinv[d];
        int pos = off[d] + atomicAdd(&cur[d], 1);
        edge2[pos] = make_uint2((u32)s, __float_as_uint(nrm));
    }
}

// fp32 -> bf16 cast (8 elems/thread)
__global__ void cast_kernel(const float* __restrict__ in, u16* __restrict__ out, long total8) {
    long i = (long)blockIdx.x * blockDim.x + threadIdx.x;
    if (i < total8) {
        const float4* p = reinterpret_cast<const float4*>(in + i * 8);
        float4 a = p[0], b = p[1];
        ushort4 o0, o1;
        o0.x = f2bf(a.x); o0.y = f2bf(a.y); o0.z = f2bf(a.z); o0.w = f2bf(a.w);
        o1.x = f2bf(b.x); o1.y = f2bf(b.y); o1.z = f2bf(b.z); o1.w = f2bf(b.w);
        ushort4* q = reinterpret_cast<ushort4*>(out + i * 8);
        q[0] = o0; q[1] = o1;
    }
}

// ---------------- W fragment repack (fp32 [K][N] -> bf16 MFMA B-fragments) ----------------
// Wf[t][s][lane][j] = bf16( W[s*32 + 8*(lane>>4) + j][t*16 + (lane&15)] )
template<int FIN, int FOUT>
__global__ void wconv_kernel(const float* __restrict__ W, u16* __restrict__ Wf) {
    int t = blockIdx.x;          // n-tile (FOUT/16)
    int s = blockIdx.y;          // k-step (FIN/32)
    int l = threadIdx.x;         // lane 0..63
    int col = t * 16 + (l & 15);
    int k0 = s * 32 + 8 * (l >> 4);
    u32 packed[4];
    for (int jj = 0; jj < 4; ++jj) {
        u16 lo = f2bf(W[(size_t)(k0 + 2 * jj) * FOUT + col]);
        u16 hi = f2bf(W[(size_t)(k0 + 2 * jj + 1) * FOUT + col]);
        packed[jj] = (u32)lo | ((u32)hi << 16);
    }
    u32* dst = (u32*)&Wf[(((size_t)t * (FIN / 32) + s) * 64 + l) * 8];
    dst[0] = packed[0]; dst[1] = packed[1]; dst[2] = packed[2]; dst[3] = packed[3];
}

// ---------------- aggregation: z = segsum(r[src]*nrm) + r*dinv^2 (bf16 in/out) ----------------
template<int F>
__global__ void agg_kernel(const u16* __restrict__ R, const int* __restrict__ off,
                           const int* __restrict__ cnt, const uint2* __restrict__ edge2,
                           const float* __restrict__ dinv, u16* __restrict__ Z, int n) {
    constexpr int TPN = F / 4;      // ushort4 per thread
    constexpr int NPB = 256 / TPN;
    int t = threadIdx.x;
    int node = blockIdx.x * NPB + t / TPN;
    if (node >= n) return;
    int j4 = (t % TPN) * 4;
    int start = off[node], num = cnt[node];
    float di = dinv[node];
    float d2 = di * di;
    ushort4 sv = *reinterpret_cast<const ushort4*>(&R[(size_t)node * F + j4]);
    float4 acc;
    acc.x = bf2f(sv.x) * d2; acc.y = bf2f(sv.y) * d2;
    acc.z = bf2f(sv.z) * d2; acc.w = bf2f(sv.w) * d2;
    for (int e = start; e < start + num; ++e) {
        uint2 ed = edge2[e];
        float w = __uint_as_float(ed.y);
        ushort4 hv = *reinterpret_cast<const ushort4*>(&R[(size_t)ed.x * F + j4]);
        acc.x += w * bf2f(hv.x);
        acc.y += w * bf2f(hv.y);
        acc.z += w * bf2f(hv.z);
        acc.w += w * bf2f(hv.w);
    }
    ushort4 o;
    o.x = f2bf(acc.x); o.y = f2bf(acc.y); o.z = f2bf(acc.z); o.w = f2bf(acc.w);
    *reinterpret_cast<ushort4*>(&Z[(size_t)node * F + j4]) = o;
}

// ---------------- MFMA GEMM: out = Z @ W + b ; Rout = bf16(relu(out)) or fused maxpool ----------------
template<int FIN, int FOUT, bool FUSE_MAX>
__global__ __launch_bounds__(256)
void gemm_kernel(const u16* __restrict__ Zin, const u16* __restrict__ Wf,
                 const float* __restrict__ b, u16* __restrict__ Rout,
                 float* __restrict__ g, int n) {
    constexpr int KS = FIN / 32;   // k-steps
    constexpr int NT = FOUT / 16;  // n-tiles
    constexpr int Q8 = FIN / 8;    // 8-elem chunks per row
    __shared__ u16 Asw[4][KS][64][8];
    __shared__ int gsm[256];
    int tid = threadIdx.x;
    int gbase = blockIdx.x * 64;

    if (FUSE_MAX) gsm[tid] = 0;

    // stage A: bf16 rows -> fragment-order LDS (16B loads/stores)
    for (int idx = tid; idx < 64 * Q8; idx += 256) {
        int m = idx / Q8, q = idx - m * Q8;
        int gn = gbase + m;
        uint4 v = make_uint4(0, 0, 0, 0);
        if (gn < n) v = *reinterpret_cast<const uint4*>(&Zin[(size_t)gn * FIN + q * 8]);
        // chunk q covers k = q*8..q*8+7 -> s = q>>2, lane_hi = q&3
        uint4* dst = reinterpret_cast<uint4*>(&Asw[m >> 4][q >> 2][((q & 3) << 4) | (m & 15)][0]);
        *dst = v;
    }
    __syncthreads();

    int w = tid >> 6, lane = tid & 63;
    int nodeq = gbase + w * 16 + ((lane >> 4) << 2);   // node for r=0

    bf16x8 a[KS];
    #pragma unroll
    for (int s = 0; s < KS; ++s)
        a[s] = *reinterpret_cast<const bf16x8*>(&Asw[w][s][lane][0]);

    int col0 = lane & 15;
    #pragma unroll
    for (int t = 0; t < NT; ++t) {
        f32x4 acc = {0.f, 0.f, 0.f, 0.f};
        #pragma unroll
        for (int s = 0; s < KS; ++s) {
            bf16x8 bf = *reinterpret_cast<const bf16x8*>(&Wf[(((size_t)t * KS + s) * 64 + lane) * 8]);
            acc = __builtin_amdgcn_mfma_f32_16x16x32_bf16(a[s], bf, acc, 0, 0, 0);
        }
        int col = t * 16 + col0;
        float bb = b[col];
        if (FUSE_MAX) {
            float ml = 0.0f;   // relu floor
            #pragma unroll
            for (int r = 0; r < 4; ++r) {
                int node = nodeq + r;
                float v = acc[r] + bb;
                if (node < n) ml = fmaxf(ml, v);
            }
            ml = fmaxf(ml, __shfl_xor(ml, 16));
            ml = fmaxf(ml, __shfl_xor(ml, 32));
            if ((lane >> 4) == 0) atomicMax(&gsm[col], __float_as_int(ml));
        } else {
            #pragma unroll
            for (int r = 0; r < 4; ++r) {
                int node = nodeq + r;
                if (node < n) {
                    float v = fmaxf(acc[r] + bb, 0.0f);   // relu
                    Rout[(size_t)node * FOUT + col] = f2bf(v);
                }
            }
        }
    }
    if (FUSE_MAX) {
        __syncthreads();
        atomicMax(&((int*)g)[tid], gsm[tid]);   // values >= 0 -> int-punned max valid
    }
}

// ---------------- head ----------------

__global__ void head_kernel(const float* __restrict__ g, const float* __restrict__ Wl1,
                            const float* __restrict__ bl1, const float* __restrict__ Wl2,
                            const float* __restrict__ bl2, float* __restrict__ out) {
    __shared__ float gs[256];
    __shared__ float ys[128];
    __shared__ float ls[10];
    int t = threadIdx.x;
    gs[t] = g[t];
    __syncthreads();
    if (t < 128) {
        float acc = bl1[t];
        for (int k = 0; k < 256; ++k) acc += gs[k] * Wl1[k * 128 + t];
        ys[t] = fmaxf(acc, 0.0f);
    }
    __syncthreads();
    if (t < 10) {
        float acc = bl2[t];
        for (int j = 0; j < 128; ++j) acc += ys[j] * Wl2[j * 10 + t];
        ls[t] = acc;
    }
    __syncthreads();
    if (t == 0) {
        float m = ls[0];
        for (int c = 1; c < 10; ++c) m = fmaxf(m, ls[c]);
        float se = 0.0f;
        for (int c = 0; c < 10; ++c) se += expf(ls[c] - m);
        float lse = logf(se);
        for (int c = 0; c < 10; ++c) out[c] = ls[c] - m - lse;
    }
}

// ---------------- launch ----------------

static inline int cdiv(int a, int b) { return (a + b - 1) / b; }

extern "C" void kernel_launch(void* const* d_in, const int* in_sizes, int n_in,
                              void* d_out, int out_size, void* d_ws, size_t ws_size,
                              hipStream_t stream) {
    const float* x   = (const float*)d_in[0];
    const int*   ei  = (const int*)d_in[1];
    const float* ew  = (const float*)d_in[2];
    const float* W1  = (const float*)d_in[3];
    const float* b1  = (const float*)d_in[4];
    const float* W2  = (const float*)d_in[5];
    const float* b2  = (const float*)d_in[6];
    const float* W3  = (const float*)d_in[7];
    const float* b3  = (const float*)d_in[8];
    const float* Wl1 = (const float*)d_in[9];
    const float* bl1 = (const float*)d_in[10];
    const float* Wl2 = (const float*)d_in[11];
    const float* bl2 = (const float*)d_in[12];

    const int n = in_sizes[0] / 128;   // 100000
    const int E = in_sizes[1] / 2;     // 1600000

    char* p = (char*)d_ws;
    auto alloc = [&](size_t bytes) { char* q = p; p += (bytes + 255) & ~(size_t)255; return q; };
    float* deg   = (float*)alloc((size_t)n * 4);
    float* dinv  = (float*)alloc((size_t)n * 4);
    int*   cnt   = (int*)  alloc((size_t)n * 4);
    int*   off   = (int*)  alloc((size_t)n * 4);
    int*   cur   = (int*)  alloc((size_t)n * 4);
    int*   bsums = (int*)  alloc(256 * 4);
    uint2* edge2 = (uint2*)alloc((size_t)E * 8);         // 12.8 MB
    u16*   xb    = (u16*)  alloc((size_t)n * 128 * 2);   // 25.6 MB
    u16*   z1    = (u16*)  alloc((size_t)n * 128 * 2);   // 25.6 MB
    u16*   r2    = (u16*)  alloc((size_t)n * 64 * 2);    // 12.8 MB
    u16*   z2    = (u16*)  alloc((size_t)n * 64 * 2);    // 12.8 MB
    u16*   r3    = (u16*)  alloc((size_t)n * 128 * 2);   // 25.6 MB
    u16*   z3    = (u16*)  alloc((size_t)n * 128 * 2);   // 25.6 MB
    u16*   W1f   = (u16*)  alloc((size_t)128 * 64 * 2);
    u16*   W2f   = (u16*)  alloc((size_t)64 * 128 * 2);
    u16*   W3f   = (u16*)  alloc((size_t)128 * 256 * 2);
    float* g     = (float*)alloc(256 * 4);
    // total ~143 MB

    hipMemsetAsync(deg, 0, (size_t)n * 4, stream);
    hipMemsetAsync(cnt, 0, (size_t)n * 4, stream);
    hipMemsetAsync(cur, 0, (size_t)n * 4, stream);
    hipMemsetAsync(g,   0, 256 * 4, stream);

    int eb = cdiv(E, 256);
    deg_cnt_kernel<<<eb, 256, 0, stream>>>(ei, ew, deg, cnt, E);
    finish_deg_kernel<<<cdiv(n, 256), 256, 0, stream>>>(deg, dinv, n);

    int nchunks = cdiv(n, 1024);   // 98
    scan_partial_kernel<<<nchunks, 256, 0, stream>>>(cnt, off, bsums, n);
    scan_sums_kernel<<<1, 128, 0, stream>>>(bsums, nchunks);
    scan_add_kernel<<<cdiv(n, 256), 256, 0, stream>>>(off, bsums, n);
    build_csr_kernel<<<eb, 256, 0, stream>>>(ei, ew, dinv, off, cur, edge2, E);

    // input cast + weight repacks (small)
    long total8 = (long)n * 128 / 8;
    cast_kernel<<<cdiv((int)total8, 256), 256, 0, stream>>>(x, xb, total8);
    wconv_kernel<128, 64><<<dim3(64 / 16, 128 / 32), 64, 0, stream>>>(W1, W1f);
    wconv_kernel<64, 128><<<dim3(128 / 16, 64 / 32), 64, 0, stream>>>(W2, W2f);
    wconv_kernel<128, 256><<<dim3(256 / 16, 128 / 32), 64, 0, stream>>>(W3, W3f);

    // layer 1: agg(x) -> z1 [128], gemm -> r2 = relu(z1@W1+b1) [64]
    agg_kernel<128><<<cdiv(n, 8), 256, 0, stream>>>(xb, off, cnt, edge2, dinv, z1, n);
    gemm_kernel<128, 64, false><<<cdiv(n, 64), 256, 0, stream>>>(z1, W1f, b1, r2, nullptr, n);
    // layer 2: agg(r2) -> z2 [64], gemm -> r3 = relu(z2@W2+b2) [128]
    agg_kernel<64><<<cdiv(n, 16), 256, 0, stream>>>(r2, off, cnt, edge2, dinv, z2, n);
    gemm_kernel<64, 128, false><<<cdiv(n, 64), 256, 0, stream>>>(z2, W2f, b2, r3, nullptr, n);
    // layer 3: agg(r3) -> z3 [128], gemm fused with global max-pool
    agg_kernel<128><<<cdiv(n, 8), 256, 0, stream>>>(r3, off, cnt, edge2, dinv, z3, n);
    gemm_kernel<128, 256, true><<<cdiv(n, 64), 256, 0, stream>>>(z3, W3f, b3, nullptr, g, n);

    head_kernel<<<1, 256, 0, stream>>>(g, Wl1, bl1, Wl2, bl2, (float*)d_out);
}

// Round 5
// 483.043 us; speedup vs baseline: 2.6625x; 1.2483x over previous
//
#include <hip/hip_runtime.h>
#include <math.h>

// GCN 3-layer + maxpool + MLP head.
// Aggregate-BEFORE-GEMM (GCN linearity): z = segsum(r[src]*norm) + r*dinv^2, r' = relu(z@W+b).
// Preprocessing: ONE u64 atomic per edge -> {cnt|deg} packed + per-edge rank; CSR scatter atomic-free.
// All inter-kernel tensors bf16. ws ~150 MB.

typedef unsigned short u16;
typedef unsigned int   u32;
typedef unsigned long long u64;

typedef short bf16x8 __attribute__((ext_vector_type(8)));
typedef float f32x4  __attribute__((ext_vector_type(4)));

__device__ __forceinline__ float bf2f(u16 u) {
    return __uint_as_float(((u32)u) << 16);
}
__device__ __forceinline__ u16 f2bf(float f) {
    u32 u = __float_as_uint(f);
    u32 r = (u + 0x7fffu + ((u >> 16) & 1u)) >> 16;   // round-nearest-even
    return (u16)r;
}

// ---------------- graph preprocessing ----------------
// pk[node*8] (64B-padded u64): high 16 bits = incoming-edge count, low 48 bits = sum(ew) in 2^-32 fixed point.
// One atomic per edge; returned old value gives this edge's rank within its dst segment.

__global__ void deg_rank_kernel(const int* __restrict__ ei, const float* __restrict__ ew,
                                u64* __restrict__ pk, u16* __restrict__ rank, int E) {
    int e = blockIdx.x * blockDim.x + threadIdx.x;
    if (e < E) {
        int d = ei[E + e];                 // dst row of edge_index [2,E]
        u64 add = (1ULL << 48) | (u64)((double)ew[e] * 4294967296.0);
        u64 old = atomicAdd(&pk[(size_t)d * 8], add);
        rank[e] = (u16)(old >> 48);
    }
}

__global__ void finish_deg_kernel(const u64* __restrict__ pk, float* __restrict__ dinv, int n) {
    int i = blockIdx.x * blockDim.x + threadIdx.x;
    if (i < n) {
        double deg = (double)(pk[(size_t)i * 8] & ((1ULL << 48) - 1)) * (1.0 / 4294967296.0);
        dinv[i] = rsqrtf((float)deg + 1.0f);
    }
}

// exclusive scan of cnt (= pk>>48) -> off[], 1024 elems per block
__global__ void scan_partial_kernel(const u64* __restrict__ pk, int* __restrict__ off,
                                    int* __restrict__ bsums, int n) {
    __shared__ int ts[256];
    int t = threadIdx.x;
    int base = blockIdx.x * 1024;
    int v[4]; int s = 0;
    for (int j = 0; j < 4; ++j) {
        int i = base + t * 4 + j;
        v[j] = (i < n) ? (int)(pk[(size_t)i * 8] >> 48) : 0;
        s += v[j];
    }
    ts[t] = s;
    __syncthreads();
    for (int st = 1; st < 256; st <<= 1) {
        int x = (t >= st) ? ts[t - st] : 0;
        __syncthreads();
        ts[t] += x;
        __syncthreads();
    }
    int excl = ts[t] - s;
    if (t == 255) bsums[blockIdx.x] = ts[255];
    int run = excl;
    for (int j = 0; j < 4; ++j) {
        int i = base + t * 4 + j;
        if (i < n) off[i] = run;
        run += v[j];
    }
}

__global__ void scan_sums_kernel(int* __restrict__ bsums, int nb) {
    __shared__ int ts[128];
    int t = threadIdx.x;
    int v = (t < nb) ? bsums[t] : 0;
    ts[t] = v;
    __syncthreads();
    for (int st = 1; st < 128; st <<= 1) {
        int x = (t >= st) ? ts[t - st] : 0;
        __syncthreads();
        ts[t] += x;
        __syncthreads();
    }
    if (t < nb) bsums[t] = ts[t] - v;   // exclusive
}

__global__ void scan_add_kernel(int* __restrict__ off, const int* __restrict__ bsums, int n) {
    int i = blockIdx.x * blockDim.x + threadIdx.x;
    if (i < n) off[i] += bsums[i >> 10];
}

// atomic-free CSR scatter: pos = off[dst] + rank[e]; edge2[pos] = {src, bits(norm)}
__global__ void build_csr_kernel(const int* __restrict__ ei, const float* __restrict__ ew,
                                 const u16* __restrict__ rank, const float* __restrict__ dinv,
                                 const int* __restrict__ off, uint2* __restrict__ edge2, int E) {
    int e = blockIdx.x * blockDim.x + threadIdx.x;
    if (e < E) {
        int s = ei[e], d = ei[E + e];
        float nrm = dinv[s] * ew[e] * dinv[d];
        int pos = off[d] + (int)rank[e];
        edge2[pos] = make_uint2((u32)s, __float_as_uint(nrm));
    }
}

// fp32 -> bf16 cast (8 elems/thread)
__global__ void cast_kernel(const float* __restrict__ in, u16* __restrict__ out, long total8) {
    long i = (long)blockIdx.x * blockDim.x + threadIdx.x;
    if (i < total8) {
        const float4* p = reinterpret_cast<const float4*>(in + i * 8);
        float4 a = p[0], b = p[1];
        ushort4 o0, o1;
        o0.x = f2bf(a.x); o0.y = f2bf(a.y); o0.z = f2bf(a.z); o0.w = f2bf(a.w);
        o1.x = f2bf(b.x); o1.y = f2bf(b.y); o1.z = f2bf(b.z); o1.w = f2bf(b.w);
        ushort4* q = reinterpret_cast<ushort4*>(out + i * 8);
        q[0] = o0; q[1] = o1;
    }
}

// ---------------- W fragment repack (fp32 [K][N] -> bf16 MFMA B-fragments) ----------------
// Wf[t][s][lane][j] = bf16( W[s*32 + 8*(lane>>4) + j][t*16 + (lane&15)] )
template<int FIN, int FOUT>
__global__ void wconv_kernel(const float* __restrict__ W, u16* __restrict__ Wf) {
    int t = blockIdx.x;          // n-tile (FOUT/16)
    int s = blockIdx.y;          // k-step (FIN/32)
    int l = threadIdx.x;         // lane 0..63
    int col = t * 16 + (l & 15);
    int k0 = s * 32 + 8 * (l >> 4);
    u32 packed[4];
    for (int jj = 0; jj < 4; ++jj) {
        u16 lo = f2bf(W[(size_t)(k0 + 2 * jj) * FOUT + col]);
        u16 hi = f2bf(W[(size_t)(k0 + 2 * jj + 1) * FOUT + col]);
        packed[jj] = (u32)lo | ((u32)hi << 16);
    }
    u32* dst = (u32*)&Wf[(((size_t)t * (FIN / 32) + s) * 64 + l) * 8];
    dst[0] = packed[0]; dst[1] = packed[1]; dst[2] = packed[2]; dst[3] = packed[3];
}

// ---------------- aggregation: z = segsum(r[src]*nrm) + r*dinv^2 (bf16 in/out) ----------------
template<int F>
__global__ void agg_kernel(const u16* __restrict__ R, const int* __restrict__ off,
                           const uint2* __restrict__ edge2,
                           const float* __restrict__ dinv, u16* __restrict__ Z, int n) {
    constexpr int TPN = F / 4;      // ushort4 per thread
    constexpr int NPB = 256 / TPN;
    int t = threadIdx.x;
    int node = blockIdx.x * NPB + t / TPN;
    if (node >= n) return;
    int j4 = (t % TPN) * 4;
    int start = off[node];
    int end = (node + 1 < n) ? off[node + 1] : off[node] ; // replaced below
    end = off[node + 1];   // off has n+1 entries (see launch: off[n] patched)
    float di = dinv[node];
    float d2 = di * di;
    ushort4 sv = *reinterpret_cast<const ushort4*>(&R[(size_t)node * F + j4]);
    float4 acc;
    acc.x = bf2f(sv.x) * d2; acc.y = bf2f(sv.y) * d2;
    acc.z = bf2f(sv.z) * d2; acc.w = bf2f(sv.w) * d2;
    for (int e = start; e < end; ++e) {
        uint2 ed = edge2[e];
        float w = __uint_as_float(ed.y);
        ushort4 hv = *reinterpret_cast<const ushort4*>(&R[(size_t)ed.x * F + j4]);
        acc.x += w * bf2f(hv.x);
        acc.y += w * bf2f(hv.y);
        acc.z += w * bf2f(hv.z);
        acc.w += w * bf2f(hv.w);
    }
    ushort4 o;
    o.x = f2bf(acc.x); o.y = f2bf(acc.y); o.z = f2bf(acc.z); o.w = f2bf(acc.w);
    *reinterpret_cast<ushort4*>(&Z[(size_t)node * F + j4]) = o;
}

__global__ void set_off_end_kernel(int* __restrict__ off, int n, int E) {
    off[n] = E;
}

// ---------------- MFMA GEMM: out = Z @ W + b ; Rout = bf16(relu(out)) or fused maxpool ----------------
template<int FIN, int FOUT, bool FUSE_MAX>
__global__ __launch_bounds__(256)
void gemm_kernel(const u16* __restrict__ Zin, const u16* __restrict__ Wf,
                 const float* __restrict__ b, u16* __restrict__ Rout,
                 float* __restrict__ g, int n) {
    constexpr int KS = FIN / 32;   // k-steps
    constexpr int NT = FOUT / 16;  // n-tiles
    constexpr int Q8 = FIN / 8;    // 8-elem chunks per row
    __shared__ u16 Asw[4][KS][64][8];
    __shared__ int gsm[256];
    int tid = threadIdx.x;
    int gbase = blockIdx.x * 64;

    if (FUSE_MAX) gsm[tid] = 0;

    // stage A: bf16 rows -> fragment-order LDS (16B loads/stores)
    for (int idx = tid; idx < 64 * Q8; idx += 256) {
        int m = idx / Q8, q = idx - m * Q8;
        int gn = gbase + m;
        uint4 v = make_uint4(0, 0, 0, 0);
        if (gn < n) v = *reinterpret_cast<const uint4*>(&Zin[(size_t)gn * FIN + q * 8]);
        // chunk q covers k = q*8..q*8+7 -> s = q>>2, lane_hi = q&3
        uint4* dst = reinterpret_cast<uint4*>(&Asw[m >> 4][q >> 2][((q & 3) << 4) | (m & 15)][0]);
        *dst = v;
    }
    __syncthreads();

    int w = tid >> 6, lane = tid & 63;
    int nodeq = gbase + w * 16 + ((lane >> 4) << 2);   // node for r=0

    bf16x8 a[KS];
    #pragma unroll
    for (int s = 0; s < KS; ++s)
        a[s] = *reinterpret_cast<const bf16x8*>(&Asw[w][s][lane][0]);

    int col0 = lane & 15;
    #pragma unroll
    for (int t = 0; t < NT; ++t) {
        f32x4 acc = {0.f, 0.f, 0.f, 0.f};
        #pragma unroll
        for (int s = 0; s < KS; ++s) {
            bf16x8 bf = *reinterpret_cast<const bf16x8*>(&Wf[(((size_t)t * KS + s) * 64 + lane) * 8]);
            acc = __builtin_amdgcn_mfma_f32_16x16x32_bf16(a[s], bf, acc, 0, 0, 0);
        }
        int col = t * 16 + col0;
        float bb = b[col];
        if (FUSE_MAX) {
            float ml = 0.0f;   // relu floor
            #pragma unroll
            for (int r = 0; r < 4; ++r) {
                int node = nodeq + r;
                float v = acc[r] + bb;
                if (node < n) ml = fmaxf(ml, v);
            }
            ml = fmaxf(ml, __shfl_xor(ml, 16));
            ml = fmaxf(ml, __shfl_xor(ml, 32));
            if ((lane >> 4) == 0) atomicMax(&gsm[col], __float_as_int(ml));
        } else {
            #pragma unroll
            for (int r = 0; r < 4; ++r) {
                int node = nodeq + r;
                if (node < n) {
                    float v = fmaxf(acc[r] + bb, 0.0f);   // relu
                    Rout[(size_t)node * FOUT + col] = f2bf(v);
                }
            }
        }
    }
    if (FUSE_MAX) {
        __syncthreads();
        atomicMax(&((int*)g)[tid], gsm[tid]);   // values >= 0 -> int-punned max valid
    }
}

// ---------------- head ----------------

__global__ void head_kernel(const float* __restrict__ g, const float* __restrict__ Wl1,
                            const float* __restrict__ bl1, const float* __restrict__ Wl2,
                            const float* __restrict__ bl2, float* __restrict__ out) {
    __shared__ float gs[256];
    __shared__ float ys[128];
    __shared__ float ls[10];
    int t = threadIdx.x;
    gs[t] = g[t];
    __syncthreads();
    if (t < 128) {
        float acc = bl1[t];
        for (int k = 0; k < 256; ++k) acc += gs[k] * Wl1[k * 128 + t];
        ys[t] = fmaxf(acc, 0.0f);
    }
    __syncthreads();
    if (t < 10) {
        float acc = bl2[t];
        for (int j = 0; j < 128; ++j) acc += ys[j] * Wl2[j * 10 + t];
        ls[t] = acc;
    }
    __syncthreads();
    if (t == 0) {
        float m = ls[0];
        for (int c = 1; c < 10; ++c) m = fmaxf(m, ls[c]);
        float se = 0.0f;
        for (int c = 0; c < 10; ++c) se += expf(ls[c] - m);
        float lse = logf(se);
        for (int c = 0; c < 10; ++c) out[c] = ls[c] - m - lse;
    }
}

// ---------------- launch ----------------

static inline int cdiv(int a, int b) { return (a + b - 1) / b; }

extern "C" void kernel_launch(void* const* d_in, const int* in_sizes, int n_in,
                              void* d_out, int out_size, void* d_ws, size_t ws_size,
                              hipStream_t stream) {
    const float* x   = (const float*)d_in[0];
    const int*   ei  = (const int*)d_in[1];
    const float* ew  = (const float*)d_in[2];
    const float* W1  = (const float*)d_in[3];
    const float* b1  = (const float*)d_in[4];
    const float* W2  = (const float*)d_in[5];
    const float* b2  = (const float*)d_in[6];
    const float* W3  = (const float*)d_in[7];
    const float* b3  = (const float*)d_in[8];
    const float* Wl1 = (const float*)d_in[9];
    const float* bl1 = (const float*)d_in[10];
    const float* Wl2 = (const float*)d_in[11];
    const float* bl2 = (const float*)d_in[12];

    const int n = in_sizes[0] / 128;   // 100000
    const int E = in_sizes[1] / 2;     // 1600000

    char* p = (char*)d_ws;
    auto alloc = [&](size_t bytes) { char* q = p; p += (bytes + 255) & ~(size_t)255; return q; };
    u64*   pk    = (u64*)  alloc((size_t)n * 64);        // 6.4 MB, one 64B line per node
    float* dinv  = (float*)alloc((size_t)n * 4);
    int*   off   = (int*)  alloc(((size_t)n + 1) * 4);
    int*   bsums = (int*)  alloc(256 * 4);
    u16*   rank  = (u16*)  alloc((size_t)E * 2);         // 3.2 MB
    uint2* edge2 = (uint2*)alloc((size_t)E * 8);         // 12.8 MB
    u16*   xb    = (u16*)  alloc((size_t)n * 128 * 2);   // 25.6 MB
    u16*   z1    = (u16*)  alloc((size_t)n * 128 * 2);   // 25.6 MB
    u16*   r2    = (u16*)  alloc((size_t)n * 64 * 2);    // 12.8 MB
    u16*   z2    = (u16*)  alloc((size_t)n * 64 * 2);    // 12.8 MB
    u16*   r3    = (u16*)  alloc((size_t)n * 128 * 2);   // 25.6 MB
    u16*   z3    = (u16*)  alloc((size_t)n * 128 * 2);   // 25.6 MB
    u16*   W1f   = (u16*)  alloc((size_t)128 * 64 * 2);
    u16*   W2f   = (u16*)  alloc((size_t)64 * 128 * 2);
    u16*   W3f   = (u16*)  alloc((size_t)128 * 256 * 2);
    float* g     = (float*)alloc(256 * 4);
    // total ~151 MB

    hipMemsetAsync(pk, 0, (size_t)n * 64, stream);
    hipMemsetAsync(g,  0, 256 * 4, stream);

    int eb = cdiv(E, 256);
    deg_rank_kernel<<<eb, 256, 0, stream>>>(ei, ew, pk, rank, E);
    finish_deg_kernel<<<cdiv(n, 256), 256, 0, stream>>>(pk, dinv, n);

    int nchunks = cdiv(n, 1024);   // 98
    scan_partial_kernel<<<nchunks, 256, 0, stream>>>(pk, off, bsums, n);
    scan_sums_kernel<<<1, 128, 0, stream>>>(bsums, nchunks);
    scan_add_kernel<<<cdiv(n, 256), 256, 0, stream>>>(off, bsums, n);
    set_off_end_kernel<<<1, 1, 0, stream>>>(off, n, E);
    build_csr_kernel<<<eb, 256, 0, stream>>>(ei, ew, rank, dinv, off, edge2, E);

    // input cast + weight repacks (small)
    long total8 = (long)n * 128 / 8;
    cast_kernel<<<cdiv((int)total8, 256), 256, 0, stream>>>(x, xb, total8);
    wconv_kernel<128, 64><<<dim3(64 / 16, 128 / 32), 64, 0, stream>>>(W1, W1f);
    wconv_kernel<64, 128><<<dim3(128 / 16, 64 / 32), 64, 0, stream>>>(W2, W2f);
    wconv_kernel<128, 256><<<dim3(256 / 16, 128 / 32), 64, 0, stream>>>(W3, W3f);

    // layer 1: agg(x) -> z1 [128], gemm -> r2 = relu(z1@W1+b1) [64]
    agg_kernel<128><<<cdiv(n, 8), 256, 0, stream>>>(xb, off, edge2, dinv, z1, n);
    gemm_kernel<128, 64, false><<<cdiv(n, 64), 256, 0, stream>>>(z1, W1f, b1, r2, nullptr, n);
    // layer 2: agg(r2) -> z2 [64], gemm -> r3 = relu(z2@W2+b2) [128]
    agg_kernel<64><<<cdiv(n, 16), 256, 0, stream>>>(r2, off, edge2, dinv, z2, n);
    gemm_kernel<64, 128, false><<<cdiv(n, 64), 256, 0, stream>>>(z2, W2f, b2, r3, nullptr, n);
    // layer 3: agg(r3) -> z3 [128], gemm fused with global max-pool
    agg_kernel<128><<<cdiv(n, 8), 256, 0, stream>>>(r3, off, edge2, dinv, z3, n);
    gemm_kernel<128, 256, true><<<cdiv(n, 64), 256, 0, stream>>>(z3, W3f, b3, nullptr, g, n);

    head_kernel<<<1, 256, 0, stream>>>(g, Wl1, bl1, Wl2, bl2, (float*)d_out);
}

// Round 6
// 379.908 us; speedup vs baseline: 3.3853x; 1.2715x over previous
//
#include <hip/hip_runtime.h>
#include <math.h>

// GCN 3-layer + maxpool + MLP head.
// Aggregate-BEFORE-GEMM (GCN linearity): z = segsum(r[src]*norm) + r*dinv^2, r' = relu(z@W+b).
// Preprocessing: ONE u64 atomic per edge -> {cnt|deg} packed + per-edge rank; CSR scatter atomic-free.
// agg: 4-way unrolled gather loop, 16B/lane rows (MLP fix, round 5).
// All inter-kernel tensors bf16. ws ~150 MB.

typedef unsigned short u16;
typedef unsigned int   u32;
typedef unsigned long long u64;

typedef short bf16x8 __attribute__((ext_vector_type(8)));
typedef float f32x4  __attribute__((ext_vector_type(4)));

__device__ __forceinline__ float bf2f(u16 u) {
    return __uint_as_float(((u32)u) << 16);
}
__device__ __forceinline__ u16 f2bf(float f) {
    u32 u = __float_as_uint(f);
    u32 r = (u + 0x7fffu + ((u >> 16) & 1u)) >> 16;   // round-nearest-even
    return (u16)r;
}

// ---------------- graph preprocessing ----------------
// pk[node*8] (64B-padded u64): high 16 bits = incoming-edge count, low 48 bits = sum(ew) in 2^-32 fixed point.
// One atomic per edge; returned old value gives this edge's rank within its dst segment.

__global__ void deg_rank_kernel(const int* __restrict__ ei, const float* __restrict__ ew,
                                u64* __restrict__ pk, u16* __restrict__ rank, int E) {
    int e = blockIdx.x * blockDim.x + threadIdx.x;
    if (e < E) {
        int d = ei[E + e];                 // dst row of edge_index [2,E]
        u64 add = (1ULL << 48) | (u64)((double)ew[e] * 4294967296.0);
        u64 old = atomicAdd(&pk[(size_t)d * 8], add);
        rank[e] = (u16)(old >> 48);
    }
}

__global__ void finish_deg_kernel(const u64* __restrict__ pk, float* __restrict__ dinv, int n) {
    int i = blockIdx.x * blockDim.x + threadIdx.x;
    if (i < n) {
        double deg = (double)(pk[(size_t)i * 8] & ((1ULL << 48) - 1)) * (1.0 / 4294967296.0);
        dinv[i] = rsqrtf((float)deg + 1.0f);
    }
}

// exclusive scan of cnt (= pk>>48) -> off[], 1024 elems per block
__global__ void scan_partial_kernel(const u64* __restrict__ pk, int* __restrict__ off,
                                    int* __restrict__ bsums, int n) {
    __shared__ int ts[256];
    int t = threadIdx.x;
    int base = blockIdx.x * 1024;
    int v[4]; int s = 0;
    for (int j = 0; j < 4; ++j) {
        int i = base + t * 4 + j;
        v[j] = (i < n) ? (int)(pk[(size_t)i * 8] >> 48) : 0;
        s += v[j];
    }
    ts[t] = s;
    __syncthreads();
    for (int st = 1; st < 256; st <<= 1) {
        int x = (t >= st) ? ts[t - st] : 0;
        __syncthreads();
        ts[t] += x;
        __syncthreads();
    }
    int excl = ts[t] - s;
    if (t == 255) bsums[blockIdx.x] = ts[255];
    int run = excl;
    for (int j = 0; j < 4; ++j) {
        int i = base + t * 4 + j;
        if (i < n) off[i] = run;
        run += v[j];
    }
}

__global__ void scan_sums_kernel(int* __restrict__ bsums, int nb) {
    __shared__ int ts[128];
    int t = threadIdx.x;
    int v = (t < nb) ? bsums[t] : 0;
    ts[t] = v;
    __syncthreads();
    for (int st = 1; st < 128; st <<= 1) {
        int x = (t >= st) ? ts[t - st] : 0;
        __syncthreads();
        ts[t] += x;
        __syncthreads();
    }
    if (t < nb) bsums[t] = ts[t] - v;   // exclusive
}

__global__ void scan_add_kernel(int* __restrict__ off, const int* __restrict__ bsums, int n, int E) {
    int i = blockIdx.x * blockDim.x + threadIdx.x;
    if (i < n) off[i] += bsums[i >> 10];
    if (i == n) off[n] = E;
}

// atomic-free CSR scatter: pos = off[dst] + rank[e]; edge2[pos] = {src, bits(norm)}
__global__ void build_csr_kernel(const int* __restrict__ ei, const float* __restrict__ ew,
                                 const u16* __restrict__ rank, const float* __restrict__ dinv,
                                 const int* __restrict__ off, uint2* __restrict__ edge2, int E) {
    int e = blockIdx.x * blockDim.x + threadIdx.x;
    if (e < E) {
        int s = ei[e], d = ei[E + e];
        float nrm = dinv[s] * ew[e] * dinv[d];
        int pos = off[d] + (int)rank[e];
        edge2[pos] = make_uint2((u32)s, __float_as_uint(nrm));
    }
}

// fp32 -> bf16 cast (8 elems/thread)
__global__ void cast_kernel(const float* __restrict__ in, u16* __restrict__ out, long total8) {
    long i = (long)blockIdx.x * blockDim.x + threadIdx.x;
    if (i < total8) {
        const float4* p = reinterpret_cast<const float4*>(in + i * 8);
        float4 a = p[0], b = p[1];
        ushort4 o0, o1;
        o0.x = f2bf(a.x); o0.y = f2bf(a.y); o0.z = f2bf(a.z); o0.w = f2bf(a.w);
        o1.x = f2bf(b.x); o1.y = f2bf(b.y); o1.z = f2bf(b.z); o1.w = f2bf(b.w);
        ushort4* q = reinterpret_cast<ushort4*>(out + i * 8);
        q[0] = o0; q[1] = o1;
    }
}

// ---------------- W fragment repack (fp32 [K][N] -> bf16 MFMA B-fragments) ----------------
// Wf[t][s][lane][j] = bf16( W[s*32 + 8*(lane>>4) + j][t*16 + (lane&15)] )
template<int FIN, int FOUT>
__global__ void wconv_kernel(const float* __restrict__ W, u16* __restrict__ Wf) {
    int t = blockIdx.x;          // n-tile (FOUT/16)
    int s = blockIdx.y;          // k-step (FIN/32)
    int l = threadIdx.x;         // lane 0..63
    int col = t * 16 + (l & 15);
    int k0 = s * 32 + 8 * (l >> 4);
    u32 packed[4];
    for (int jj = 0; jj < 4; ++jj) {
        u16 lo = f2bf(W[(size_t)(k0 + 2 * jj) * FOUT + col]);
        u16 hi = f2bf(W[(size_t)(k0 + 2 * jj + 1) * FOUT + col]);
        packed[jj] = (u32)lo | ((u32)hi << 16);
    }
    u32* dst = (u32*)&Wf[(((size_t)t * (FIN / 32) + s) * 64 + l) * 8];
    dst[0] = packed[0]; dst[1] = packed[1]; dst[2] = packed[2]; dst[3] = packed[3];
}

// ---------------- aggregation: z = segsum(r[src]*nrm) + r*dinv^2 (bf16 in/out) ----------------
// 16B/lane rows, 4-way unrolled gather loop for MLP.
template<int F>
__global__ __launch_bounds__(256)
void agg_kernel(const u16* __restrict__ R, const int* __restrict__ off,
                const uint2* __restrict__ edge2,
                const float* __restrict__ dinv, u16* __restrict__ Z, int n) {
    constexpr int TPN = F / 8;      // 8 bf16 (16B) per thread
    constexpr int NPB = 256 / TPN;
    int t = threadIdx.x;
    int node = blockIdx.x * NPB + t / TPN;
    if (node >= n) return;
    int j8 = (t % TPN) * 8;
    int start = off[node];
    int end   = off[node + 1];
    float di = dinv[node];
    float d2 = di * di;

    const u16* rowp = &R[(size_t)node * F + j8];
    uint4 sv = *reinterpret_cast<const uint4*>(rowp);
    float acc0, acc1, acc2, acc3, acc4, acc5, acc6, acc7;
    {
        u32 a0 = sv.x, a1 = sv.y, a2 = sv.z, a3 = sv.w;
        acc0 = bf2f((u16)a0) * d2;        acc1 = bf2f((u16)(a0 >> 16)) * d2;
        acc2 = bf2f((u16)a1) * d2;        acc3 = bf2f((u16)(a1 >> 16)) * d2;
        acc4 = bf2f((u16)a2) * d2;        acc5 = bf2f((u16)(a2 >> 16)) * d2;
        acc6 = bf2f((u16)a3) * d2;        acc7 = bf2f((u16)(a3 >> 16)) * d2;
    }

    int e = start;
    for (; e + 4 <= end; e += 4) {
        uint2 ed0 = edge2[e];
        uint2 ed1 = edge2[e + 1];
        uint2 ed2 = edge2[e + 2];
        uint2 ed3 = edge2[e + 3];
        uint4 h0 = *reinterpret_cast<const uint4*>(&R[(size_t)ed0.x * F + j8]);
        uint4 h1 = *reinterpret_cast<const uint4*>(&R[(size_t)ed1.x * F + j8]);
        uint4 h2 = *reinterpret_cast<const uint4*>(&R[(size_t)ed2.x * F + j8]);
        uint4 h3 = *reinterpret_cast<const uint4*>(&R[(size_t)ed3.x * F + j8]);
        float w0 = __uint_as_float(ed0.y);
        float w1 = __uint_as_float(ed1.y);
        float w2 = __uint_as_float(ed2.y);
        float w3 = __uint_as_float(ed3.y);
        acc0 += w0 * bf2f((u16)h0.x) + w1 * bf2f((u16)h1.x) + w2 * bf2f((u16)h2.x) + w3 * bf2f((u16)h3.x);
        acc1 += w0 * bf2f((u16)(h0.x >> 16)) + w1 * bf2f((u16)(h1.x >> 16)) + w2 * bf2f((u16)(h2.x >> 16)) + w3 * bf2f((u16)(h3.x >> 16));
        acc2 += w0 * bf2f((u16)h0.y) + w1 * bf2f((u16)h1.y) + w2 * bf2f((u16)h2.y) + w3 * bf2f((u16)h3.y);
        acc3 += w0 * bf2f((u16)(h0.y >> 16)) + w1 * bf2f((u16)(h1.y >> 16)) + w2 * bf2f((u16)(h2.y >> 16)) + w3 * bf2f((u16)(h3.y >> 16));
        acc4 += w0 * bf2f((u16)h0.z) + w1 * bf2f((u16)h1.z) + w2 * bf2f((u16)h2.z) + w3 * bf2f((u16)h3.z);
        acc5 += w0 * bf2f((u16)(h0.z >> 16)) + w1 * bf2f((u16)(h1.z >> 16)) + w2 * bf2f((u16)(h2.z >> 16)) + w3 * bf2f((u16)(h3.z >> 16));
        acc6 += w0 * bf2f((u16)h0.w) + w1 * bf2f((u16)h1.w) + w2 * bf2f((u16)h2.w) + w3 * bf2f((u16)h3.w);
        acc7 += w0 * bf2f((u16)(h0.w >> 16)) + w1 * bf2f((u16)(h1.w >> 16)) + w2 * bf2f((u16)(h2.w >> 16)) + w3 * bf2f((u16)(h3.w >> 16));
    }
    for (; e < end; ++e) {
        uint2 ed = edge2[e];
        float w = __uint_as_float(ed.y);
        uint4 hv = *reinterpret_cast<const uint4*>(&R[(size_t)ed.x * F + j8]);
        acc0 += w * bf2f((u16)hv.x);  acc1 += w * bf2f((u16)(hv.x >> 16));
        acc2 += w * bf2f((u16)hv.y);  acc3 += w * bf2f((u16)(hv.y >> 16));
        acc4 += w * bf2f((u16)hv.z);  acc5 += w * bf2f((u16)(hv.z >> 16));
        acc6 += w * bf2f((u16)hv.w);  acc7 += w * bf2f((u16)(hv.w >> 16));
    }

    uint4 o;
    o.x = (u32)f2bf(acc0) | ((u32)f2bf(acc1) << 16);
    o.y = (u32)f2bf(acc2) | ((u32)f2bf(acc3) << 16);
    o.z = (u32)f2bf(acc4) | ((u32)f2bf(acc5) << 16);
    o.w = (u32)f2bf(acc6) | ((u32)f2bf(acc7) << 16);
    *reinterpret_cast<uint4*>(&Z[(size_t)node * F + j8]) = o;
}

// ---------------- MFMA GEMM: out = Z @ W + b ; Rout = bf16(relu(out)) or fused maxpool ----------------
template<int FIN, int FOUT, bool FUSE_MAX>
__global__ __launch_bounds__(256)
void gemm_kernel(const u16* __restrict__ Zin, const u16* __restrict__ Wf,
                 const float* __restrict__ b, u16* __restrict__ Rout,
                 float* __restrict__ g, int n) {
    constexpr int KS = FIN / 32;   // k-steps
    constexpr int NT = FOUT / 16;  // n-tiles
    constexpr int Q8 = FIN / 8;    // 8-elem chunks per row
    __shared__ u16 Asw[4][KS][64][8];
    __shared__ int gsm[256];
    int tid = threadIdx.x;
    int gbase = blockIdx.x * 64;

    if (FUSE_MAX) gsm[tid] = 0;

    // stage A: bf16 rows -> fragment-order LDS (16B loads/stores)
    for (int idx = tid; idx < 64 * Q8; idx += 256) {
        int m = idx / Q8, q = idx - m * Q8;
        int gn = gbase + m;
        uint4 v = make_uint4(0, 0, 0, 0);
        if (gn < n) v = *reinterpret_cast<const uint4*>(&Zin[(size_t)gn * FIN + q * 8]);
        // chunk q covers k = q*8..q*8+7 -> s = q>>2, lane_hi = q&3
        uint4* dst = reinterpret_cast<uint4*>(&Asw[m >> 4][q >> 2][((q & 3) << 4) | (m & 15)][0]);
        *dst = v;
    }
    __syncthreads();

    int w = tid >> 6, lane = tid & 63;
    int nodeq = gbase + w * 16 + ((lane >> 4) << 2);   // node for r=0

    bf16x8 a[KS];
    #pragma unroll
    for (int s = 0; s < KS; ++s)
        a[s] = *reinterpret_cast<const bf16x8*>(&Asw[w][s][lane][0]);

    int col0 = lane & 15;
    #pragma unroll
    for (int t = 0; t < NT; ++t) {
        f32x4 acc = {0.f, 0.f, 0.f, 0.f};
        #pragma unroll
        for (int s = 0; s < KS; ++s) {
            bf16x8 bf = *reinterpret_cast<const bf16x8*>(&Wf[(((size_t)t * KS + s) * 64 + lane) * 8]);
            acc = __builtin_amdgcn_mfma_f32_16x16x32_bf16(a[s], bf, acc, 0, 0, 0);
        }
        int col = t * 16 + col0;
        float bb = b[col];
        if (FUSE_MAX) {
            float ml = 0.0f;   // relu floor
            #pragma unroll
            for (int r = 0; r < 4; ++r) {
                int node = nodeq + r;
                float v = acc[r] + bb;
                if (node < n) ml = fmaxf(ml, v);
            }
            ml = fmaxf(ml, __shfl_xor(ml, 16));
            ml = fmaxf(ml, __shfl_xor(ml, 32));
            if ((lane >> 4) == 0) atomicMax(&gsm[col], __float_as_int(ml));
        } else {
            #pragma unroll
            for (int r = 0; r < 4; ++r) {
                int node = nodeq + r;
                if (node < n) {
                    float v = fmaxf(acc[r] + bb, 0.0f);   // relu
                    Rout[(size_t)node * FOUT + col] = f2bf(v);
                }
            }
        }
    }
    if (FUSE_MAX) {
        __syncthreads();
        atomicMax(&((int*)g)[tid], gsm[tid]);   // values >= 0 -> int-punned max valid
    }
}

// ---------------- head ----------------

__global__ void head_kernel(const float* __restrict__ g, const float* __restrict__ Wl1,
                            const float* __restrict__ bl1, const float* __restrict__ Wl2,
                            const float* __restrict__ bl2, float* __restrict__ out) {
    __shared__ float gs[256];
    __shared__ float ys[128];
    __shared__ float ls[10];
    int t = threadIdx.x;
    gs[t] = g[t];
    __syncthreads();
    if (t < 128) {
        float acc = bl1[t];
        for (int k = 0; k < 256; ++k) acc += gs[k] * Wl1[k * 128 + t];
        ys[t] = fmaxf(acc, 0.0f);
    }
    __syncthreads();
    if (t < 10) {
        float acc = bl2[t];
        for (int j = 0; j < 128; ++j) acc += ys[j] * Wl2[j * 10 + t];
        ls[t] = acc;
    }
    __syncthreads();
    if (t == 0) {
        float m = ls[0];
        for (int c = 1; c < 10; ++c) m = fmaxf(m, ls[c]);
        float se = 0.0f;
        for (int c = 0; c < 10; ++c) se += expf(ls[c] - m);
        float lse = logf(se);
        for (int c = 0; c < 10; ++c) out[c] = ls[c] - m - lse;
    }
}

// ---------------- launch ----------------

static inline int cdiv(int a, int b) { return (a + b - 1) / b; }

extern "C" void kernel_launch(void* const* d_in, const int* in_sizes, int n_in,
                              void* d_out, int out_size, void* d_ws, size_t ws_size,
                              hipStream_t stream) {
    const float* x   = (const float*)d_in[0];
    const int*   ei  = (const int*)d_in[1];
    const float* ew  = (const float*)d_in[2];
    const float* W1  = (const float*)d_in[3];
    const float* b1  = (const float*)d_in[4];
    const float* W2  = (const float*)d_in[5];
    const float* b2  = (const float*)d_in[6];
    const float* W3  = (const float*)d_in[7];
    const float* b3  = (const float*)d_in[8];
    const float* Wl1 = (const float*)d_in[9];
    const float* bl1 = (const float*)d_in[10];
    const float* Wl2 = (const float*)d_in[11];
    const float* bl2 = (const float*)d_in[12];

    const int n = in_sizes[0] / 128;   // 100000
    const int E = in_sizes[1] / 2;     // 1600000

    char* p = (char*)d_ws;
    auto alloc = [&](size_t bytes) { char* q = p; p += (bytes + 255) & ~(size_t)255; return q; };
    u64*   pk    = (u64*)  alloc((size_t)n * 64);        // 6.4 MB, one 64B line per node
    float* dinv  = (float*)alloc((size_t)n * 4);
    int*   off   = (int*)  alloc(((size_t)n + 1) * 4);
    int*   bsums = (int*)  alloc(256 * 4);
    u16*   rank  = (u16*)  alloc((size_t)E * 2);         // 3.2 MB
    uint2* edge2 = (uint2*)alloc((size_t)E * 8);         // 12.8 MB
    u16*   xb    = (u16*)  alloc((size_t)n * 128 * 2);   // 25.6 MB
    u16*   z1    = (u16*)  alloc((size_t)n * 128 * 2);   // 25.6 MB
    u16*   r2    = (u16*)  alloc((size_t)n * 64 * 2);    // 12.8 MB
    u16*   z2    = (u16*)  alloc((size_t)n * 64 * 2);    // 12.8 MB
    u16*   r3    = (u16*)  alloc((size_t)n * 128 * 2);   // 25.6 MB
    u16*   z3    = (u16*)  alloc((size_t)n * 128 * 2);   // 25.6 MB
    u16*   W1f   = (u16*)  alloc((size_t)128 * 64 * 2);
    u16*   W2f   = (u16*)  alloc((size_t)64 * 128 * 2);
    u16*   W3f   = (u16*)  alloc((size_t)128 * 256 * 2);
    float* g     = (float*)alloc(256 * 4);
    // total ~151 MB

    hipMemsetAsync(pk, 0, (size_t)n * 64, stream);
    hipMemsetAsync(g,  0, 256 * 4, stream);

    int eb = cdiv(E, 256);
    deg_rank_kernel<<<eb, 256, 0, stream>>>(ei, ew, pk, rank, E);
    finish_deg_kernel<<<cdiv(n, 256), 256, 0, stream>>>(pk, dinv, n);

    int nchunks = cdiv(n, 1024);   // 98
    scan_partial_kernel<<<nchunks, 256, 0, stream>>>(pk, off, bsums, n);
    scan_sums_kernel<<<1, 128, 0, stream>>>(bsums, nchunks);
    scan_add_kernel<<<cdiv(n + 1, 256), 256, 0, stream>>>(off, bsums, n, E);
    build_csr_kernel<<<eb, 256, 0, stream>>>(ei, ew, rank, dinv, off, edge2, E);

    // input cast + weight repacks (small)
    long total8 = (long)n * 128 / 8;
    cast_kernel<<<cdiv((int)total8, 256), 256, 0, stream>>>(x, xb, total8);
    wconv_kernel<128, 64><<<dim3(64 / 16, 128 / 32), 64, 0, stream>>>(W1, W1f);
    wconv_kernel<64, 128><<<dim3(128 / 16, 64 / 32), 64, 0, stream>>>(W2, W2f);
    wconv_kernel<128, 256><<<dim3(256 / 16, 128 / 32), 64, 0, stream>>>(W3, W3f);

    // layer 1: agg(x) -> z1 [128], gemm -> r2 = relu(z1@W1+b1) [64]
    agg_kernel<128><<<cdiv(n, 16), 256, 0, stream>>>(xb, off, edge2, dinv, z1, n);
    gemm_kernel<128, 64, false><<<cdiv(n, 64), 256, 0, stream>>>(z1, W1f, b1, r2, nullptr, n);
    // layer 2: agg(r2) -> z2 [64], gemm -> r3 = relu(z2@W2+b2) [128]
    agg_kernel<64><<<cdiv(n, 32), 256, 0, stream>>>(r2, off, edge2, dinv, z2, n);
    gemm_kernel<64, 128, false><<<cdiv(n, 64), 256, 0, stream>>>(z2, W2f, b2, r3, nullptr, n);
    // layer 3: agg(r3) -> z3 [128], gemm fused with global max-pool
    agg_kernel<128><<<cdiv(n, 16), 256, 0, stream>>>(r3, off, edge2, dinv, z3, n);
    gemm_kernel<128, 256, true><<<cdiv(n, 64), 256, 0, stream>>>(z3, W3f, b3, nullptr, g, n);

    head_kernel<<<1, 256, 0, stream>>>(g, Wl1, bl1, Wl2, bl2, (float*)d_out);
}